// Round 7
// baseline (224.068 us; speedup 1.0000x reference)
//
#include <hip/hip_runtime.h>
#include <hip/hip_bf16.h>

// NCA update, round 7: Y single-bf16 (W1/W2 still split hi+lo), LDS-staged
// horizontal exchange (no shuffles), 8B-granule conflict-free swizzle,
// transposed L2 GEMM for a float4 epilogue.

#define CCH 16
#define HID 128
#define HH 256
#define WW 256
#define BB 32

typedef __attribute__((ext_vector_type(8))) short bf16x8;
typedef __attribute__((ext_vector_type(4))) float f32x4;
typedef __attribute__((ext_vector_type(4))) int i32x4;
typedef __attribute__((ext_vector_type(2))) unsigned int u32x2;

union bfpack {
  u32x2 w2[2];
  bf16x8 v;
};

__device__ inline unsigned short f2bf(float f) {  // RNE
  unsigned int u = __float_as_uint(f);
  u += 0x7FFFu + ((u >> 16) & 1u);
  return (unsigned short)(u >> 16);
}
__device__ inline float bf2f(unsigned short s) {
  return __uint_as_float(((unsigned int)s) << 16);
}
__device__ inline unsigned int cvtpk2(float a, float b) {  // v_cvt_pk_bf16_f32
  union { __hip_bfloat162 h; unsigned int u; } cv;
  cv.h = __float22bfloat162_rn(make_float2(a, b));
  return cv.u;
}

// ---------------------------------------------------------------- prep
// w1p[(((pl*2+ks)*8 + mt)*64 + lane)*8 + j]; row = mt*16+(l&15),
// k = ks*32+(l>>4)*8+j; k>=48 zeroed (pairs with the dup-B-read trick).
__global__ __launch_bounds__(256) void pack_w1_kernel(
    const float* __restrict__ w1, unsigned short* __restrict__ w1p) {
  const int tid = blockIdx.x * 256 + threadIdx.x;
  if (tid >= 2048) return;
  const int l = tid & 63, m = (tid >> 6) & 7, ks = (tid >> 9) & 1,
            pl = (tid >> 10) & 1;
  const int row = m * 16 + (l & 15);
  const int kb = ks * 32 + (l >> 4) * 8;
  const size_t off = ((((size_t)pl * 2 + ks) * 8 + m) * 64 + l) * 8;
#pragma unroll
  for (int j = 0; j < 8; ++j) {
    const int k = kb + j;
    const float v = (k < 48) ? w1[row * 48 + k] : 0.0f;
    const unsigned short hi = f2bf(v);
    w1p[off + j] = (pl == 0) ? hi : f2bf(v - bf2f(hi));
  }
}

// w2p[((pl*4+ks)*64 + lane)*8 + j]; out-ch = l&15, k = ks*32+(l>>4)*8+j.
// (A- and B-fragment layouts coincide, so this serves as the B operand of
// the transposed L2 GEMM unchanged.)
__global__ __launch_bounds__(256) void pack_w2_kernel(
    const float* __restrict__ w2, unsigned short* __restrict__ w2p) {
  const int tid = blockIdx.x * 256 + threadIdx.x;
  if (tid >= 512) return;
  const int l = tid & 63, ks = (tid >> 6) & 3, pl = (tid >> 8) & 1;
  const int row = l & 15;
  const int kb = ks * 32 + (l >> 4) * 8;
  const size_t off = (((size_t)pl * 4 + ks) * 64 + l) * 8;
#pragma unroll
  for (int j = 0; j < 8; ++j) {
    const float v = w2[row * 128 + kb + j];
    const unsigned short hi = f2bf(v);
    w2p[off + j] = (pl == 0) ? hi : f2bf(v - bf2f(hi));
  }
}

// ---------------------------------------------------------------- main
// Block = 128 px (half row), 512 thr = 8 waves; wave wv: nw = wv&1 (px half),
// chq = wv>>1 (4 channels in phase 1, 2 M-tiles in phase 2).
// LDS 33552 B:
//  rows [0,32768): row px (256 B):
//    bytes [0,96)  nominal: Y bf16 [48 k], 8B-granule XOR swizzle (px&15)<<3
//                  (phase 3 overwrites the whole row with H[128] bf16);
//    bytes [128,256): a/b staging f32: a@128+chq*16, b@192+chq*16,
//                  16B-granule XOR swizzle (px&7)<<4.
//  [32768,33024): halo a/b rows (2 x 128 B, unswizzled).
//  [33024,33544): cm[130] f32 alpha column-max.
__global__ __launch_bounds__(512, 4) void nca_mfma_kernel(
    const float* __restrict__ x, const float* __restrict__ b1,
    const float* __restrict__ b2, const unsigned short* __restrict__ w1p,
    const unsigned short* __restrict__ w2p, const int* __restrict__ fire,
    float* __restrict__ out, float* __restrict__ alpha_ws,
    unsigned char* __restrict__ pre_ws) {
  __shared__ __align__(16) unsigned char smem[33552];
  float* cm = (float*)(smem + 33024);

  const int L = blockIdx.x;
  const int orig = ((L & 7) << 11) + (L >> 3);  // XCD-contiguous (16384=8*2048)
  const int b = orig >> 9;
  const int h = (orig >> 1) & 255;
  const int wt = orig & 1;
  const int tid = threadIdx.x;
  const int wv = tid >> 6, lane = tid & 63, g = lane >> 4, ln = lane & 15;
  const int nw = wv & 1;
  const int chq = wv >> 1;
  const int c0 = chq * 4;
  const int px = nw * 64 + lane;
  const int gcol = wt * 128 + px;
  const int hm = (h + 255) & 255, hp = (h + 1) & 255;

  // ---- phase 1a: per-thread vertical filter -> a/b staging in LDS.
  f32x4 av, bv, iv;
  float cmax = 0.0f;
  const float* xb0 = x + ((size_t)b * CCH + c0) * (HH * WW);
  {
    const int o_t = hm * WW + gcol, o_m = h * WW + gcol, o_b = hp * WW + gcol;
#pragma unroll
    for (int j = 0; j < 4; ++j) {
      const float* xc = xb0 + (size_t)j * (HH * WW);
      const float t = xc[o_t], m = xc[o_m], bo = xc[o_b];
      av[j] = 0.125f * (t + bo) + 0.25f * m;
      bv[j] = 0.125f * (bo - t);
      iv[j] = m;
      if (chq == 0 && j == 3) cmax = fmaxf(fmaxf(t, m), bo);
    }
    const int sw16 = (px & 7) << 4;
    *(f32x4*)(smem + px * 256 + 128 + ((chq * 16) ^ sw16)) = av;
    *(f32x4*)(smem + px * 256 + 128 + ((64 + chq * 16) ^ sw16)) = bv;
    if (chq == 0) cm[px + 1] = cmax;
  }
  // Halo columns (outside the block) -> halo rows.
  {
    const bool hL = (nw == 0 && lane == 0), hR = (nw == 1 && lane == 63);
    if (hL || hR) {
      const int side = hR ? 1 : 0;
      const int gc = hR ? ((wt * 128 + 128) & 255) : ((wt * 128 + 255) & 255);
      const int o_t = hm * WW + gc, o_m = h * WW + gc, o_b = hp * WW + gc;
      f32x4 ha, hb;
      float hcm = 0.0f;
#pragma unroll
      for (int j = 0; j < 4; ++j) {
        const float* xc = xb0 + (size_t)j * (HH * WW);
        const float t = xc[o_t], m = xc[o_m], bo = xc[o_b];
        ha[j] = 0.125f * (t + bo) + 0.25f * m;
        hb[j] = 0.125f * (bo - t);
        if (chq == 0 && j == 3) hcm = fmaxf(fmaxf(t, m), bo);
      }
      *(f32x4*)(smem + 32768 + side * 128 + chq * 16) = ha;
      *(f32x4*)(smem + 32768 + side * 128 + 64 + chq * 16) = hb;
      if (chq == 0) cm[side ? 129 : 0] = hcm;
    }
  }
  __syncthreads();

  // ---- phase 1b: horizontal filter from staged neighbors -> Y bf16.
  {
    const int rl = px - 1, rr = px + 1;
    const unsigned char* baseL =
        (px == 0) ? (smem + 32768) : (smem + rl * 256 + 128);
    const int swL = (px == 0) ? 0 : ((rl & 7) << 4);
    const unsigned char* baseR =
        (px == 127) ? (smem + 32768 + 128) : (smem + rr * 256 + 128);
    const int swR = (px == 127) ? 0 : ((rr & 7) << 4);
    const f32x4 aL = *(const f32x4*)(baseL + ((chq * 16) ^ swL));
    const f32x4 bL = *(const f32x4*)(baseL + ((64 + chq * 16) ^ swL));
    const f32x4 aR = *(const f32x4*)(baseR + ((chq * 16) ^ swR));
    const f32x4 bR = *(const f32x4*)(baseR + ((64 + chq * 16) ^ swR));

    float yv[12];
#pragma unroll
    for (int j = 0; j < 4; ++j) {
      yv[j * 3 + 0] = iv[j];
      yv[j * 3 + 1] = aR[j] - aL[j];
      yv[j * 3 + 2] = bL[j] + 2.0f * bv[j] + bR[j];
    }
    unsigned int hw[6];
#pragma unroll
    for (int i = 0; i < 6; ++i) hw[i] = cvtpk2(yv[2 * i], yv[2 * i + 1]);
    const int sw8 = (px & 15) << 3;
    unsigned char* rb = smem + px * 256;
    const int o0 = c0 * 6;  // byte offset of this thread's 12 k-slots
    *(u32x2*)(rb + ((o0) ^ sw8)) = (u32x2){hw[0], hw[1]};
    *(u32x2*)(rb + ((o0 + 8) ^ sw8)) = (u32x2){hw[2], hw[3]};
    *(u32x2*)(rb + ((o0 + 16) ^ sw8)) = (u32x2){hw[4], hw[5]};

    if (chq == 0) {  // pre-life from alpha column-max (px-1, px, px+1)
      const float cl = cm[px], cr = cm[px + 2];
      const size_t pix = ((size_t)b * HH + h) * WW + gcol;
      pre_ws[pix] = (fmaxf(fmaxf(cl, cmax), cr) > 0.1f) ? 1 : 0;
    }
  }
  __syncthreads();

  // ---- phase 2: L1 GEMM (W split hi+lo, Y single). Wave = (chq: 2 mt) x
  // (nw: 4 px-tiles).
  bf16x8 A1[2][4];  // [mi][hi-k0, hi-k1, lo-k0, lo-k1]
#pragma unroll
  for (int mi = 0; mi < 2; ++mi)
#pragma unroll
    for (int f = 0; f < 4; ++f)
      A1[mi][f] = *(const bf16x8*)(
          w1p + (((size_t)f * 8 + (chq * 2 + mi)) * 64 + lane) * 8);

  f32x4 acc[2][4];
#pragma unroll
  for (int mi = 0; mi < 2; ++mi)
#pragma unroll
    for (int ni = 0; ni < 4; ++ni) acc[mi][ni] = (f32x4){0.f, 0.f, 0.f, 0.f};

#pragma unroll
  for (int ni = 0; ni < 4; ++ni) {
    const int pxb = (nw * 4 + ni) * 16 + ln;
    const int sw8 = ln << 3;  // pxb&15 == ln
    const unsigned char* rb = smem + pxb * 256;
    const int o0 = g * 16;
    const int o1 = (g < 2) ? (64 + g * 16) : ((g - 2) * 16);  // dup-read pad
    bfpack B0, B1;
    B0.w2[0] = *(const u32x2*)(rb + (o0 ^ sw8));
    B0.w2[1] = *(const u32x2*)(rb + ((o0 + 8) ^ sw8));
    B1.w2[0] = *(const u32x2*)(rb + (o1 ^ sw8));
    B1.w2[1] = *(const u32x2*)(rb + ((o1 + 8) ^ sw8));
#pragma unroll
    for (int mi = 0; mi < 2; ++mi) {
      f32x4 a = acc[mi][ni];
      a = __builtin_amdgcn_mfma_f32_16x16x32_bf16(A1[mi][0], B0.v, a, 0, 0, 0);
      a = __builtin_amdgcn_mfma_f32_16x16x32_bf16(A1[mi][1], B1.v, a, 0, 0, 0);
      a = __builtin_amdgcn_mfma_f32_16x16x32_bf16(A1[mi][2], B0.v, a, 0, 0, 0);
      a = __builtin_amdgcn_mfma_f32_16x16x32_bf16(A1[mi][3], B1.v, a, 0, 0, 0);
      acc[mi][ni] = a;
    }
  }
  __syncthreads();  // all Y reads done before H overwrites

  // ---- phase 3: bias+relu -> H bf16 (8B swizzled stores).
#pragma unroll
  for (int mi = 0; mi < 2; ++mi) {
    const int hid0 = (chq * 2 + mi) * 16 + g * 4;
    const f32x4 b1v = *(const f32x4*)(b1 + hid0);
#pragma unroll
    for (int ni = 0; ni < 4; ++ni) {
      const int pxb = (nw * 4 + ni) * 16 + ln;
      const f32x4 a = acc[mi][ni];
      u32x2 hv;
      hv[0] = cvtpk2(fmaxf(a[0] + b1v[0], 0.f), fmaxf(a[1] + b1v[1], 0.f));
      hv[1] = cvtpk2(fmaxf(a[2] + b1v[2], 0.f), fmaxf(a[3] + b1v[3], 0.f));
      *(u32x2*)(smem + pxb * 256 + ((hid0 * 2) ^ (ln << 3))) = hv;
    }
  }
  __syncthreads();  // H complete before cross-wave reads

  // ---- phase 4: transposed L2 GEMM (A = H, B = W2) + float4 epilogue.
  bf16x8 A2[8];  // B-operand frags: [pl*4+ks]
#pragma unroll
  for (int i = 0; i < 8; ++i)
    A2[i] = *(const bf16x8*)(w2p + ((size_t)i * 64 + lane) * 8);

  {
    const int prow = wv * 16 + ln;  // A-frag row = px
    const unsigned char* rb = smem + prow * 256;
    const int sw8 = ln << 3;
    f32x4 a = (f32x4){0.f, 0.f, 0.f, 0.f};
#pragma unroll
    for (int ks = 0; ks < 4; ++ks) {
      const int o = ks * 64 + g * 16;
      bfpack Hf;
      Hf.w2[0] = *(const u32x2*)(rb + (o ^ sw8));
      Hf.w2[1] = *(const u32x2*)(rb + ((o + 8) ^ sw8));
      a = __builtin_amdgcn_mfma_f32_16x16x32_bf16(Hf.v, A2[ks], a, 0, 0, 0);
      a = __builtin_amdgcn_mfma_f32_16x16x32_bf16(Hf.v, A2[4 + ks], a, 0, 0, 0);
    }
    // C-frag: ch = ln, px = wv*16 + g*4 + r -> vectorized epilogue.
    const int px0 = wv * 16 + g * 4;
    const int wg0 = wt * 128 + px0;
    const size_t pix0 = ((size_t)b * HH + h) * WW + wg0;
    const i32x4 fi = *(const i32x4*)(fire + pix0);
    const float b2v = b2[ln];
    const size_t xi0 = (((size_t)(b * CCH + ln)) * HH + h) * WW + wg0;
    const f32x4 xo = *(const f32x4*)(x + xi0);
    f32x4 v;
#pragma unroll
    for (int r = 0; r < 4; ++r) v[r] = xo[r] + (a[r] + b2v) * (float)fi[r];
    *(f32x4*)(out + xi0) = v;
    if (ln == 3) *(f32x4*)(alpha_ws + pix0) = v;
  }
}

// ---------------------------------------------------------------- life
__global__ __launch_bounds__(256) void life_mask_kernel(
    const float* __restrict__ alpha_ws, const unsigned char* __restrict__ pre_ws,
    float* __restrict__ out) {
  const int bh = blockIdx.x;
  const int b = bh >> 8;
  const int h = bh & 255;
  const int w = threadIdx.x;
  const int hm = (h + 255) & 255;
  const int hp = (h + 1) & 255;
  const int wm = (w + 255) & 255;
  const int wp = (w + 1) & 255;

  const float* ab = alpha_ws + (size_t)b * HH * WW;
  float m = ab[(size_t)hm * WW + wm];
  m = fmaxf(m, ab[(size_t)hm * WW + w]);
  m = fmaxf(m, ab[(size_t)hm * WW + wp]);
  m = fmaxf(m, ab[(size_t)h * WW + wm]);
  m = fmaxf(m, ab[(size_t)h * WW + w]);
  m = fmaxf(m, ab[(size_t)h * WW + wp]);
  m = fmaxf(m, ab[(size_t)hp * WW + wm]);
  m = fmaxf(m, ab[(size_t)hp * WW + w]);
  m = fmaxf(m, ab[(size_t)hp * WW + wp]);

  const size_t pix = ((size_t)b * HH + h) * WW + w;
  const bool post = m > 0.1f;
  const bool pre = pre_ws[pix] != 0;
  if (!(pre && post)) {
#pragma unroll
    for (int c = 0; c < CCH; ++c)
      out[((size_t)(b * CCH + c) * HH + h) * WW + w] = 0.0f;
  }
}

// ---------------------------------------------------------------- launch
extern "C" void kernel_launch(void* const* d_in, const int* in_sizes, int n_in,
                              void* d_out, int out_size, void* d_ws,
                              size_t ws_size, hipStream_t stream) {
  const float* x = (const float*)d_in[0];
  const float* w1 = (const float*)d_in[1];
  const float* b1 = (const float*)d_in[2];
  const float* w2 = (const float*)d_in[3];
  const float* b2 = (const float*)d_in[4];
  const int* fire = (const int*)d_in[5];
  float* out = (float*)d_out;

  const size_t npix = (size_t)BB * HH * WW;
  unsigned short* w1p = (unsigned short*)d_ws;
  unsigned short* w2p = (unsigned short*)((char*)d_ws + 32768);
  float* alpha_ws = (float*)((char*)d_ws + 40960);
  unsigned char* pre_ws = (unsigned char*)d_ws + 40960 + npix * sizeof(float);

  pack_w1_kernel<<<8, 256, 0, stream>>>(w1, w1p);
  pack_w2_kernel<<<2, 256, 0, stream>>>(w2, w2p);
  nca_mfma_kernel<<<BB * HH * 2, 512, 0, stream>>>(x, b1, b2, w1p, w2p, fire,
                                                   out, alpha_ws, pre_ws);
  life_mask_kernel<<<BB * HH, 256, 0, stream>>>(alpha_ws, pre_ws, out);
}